// Round 8
// baseline (351.022 us; speedup 1.0000x reference)
//
#include <hip/hip_runtime.h>

// ---------------------------------------------------------------------------
// Soft decision tree forward (all-f16 pipeline), round 8.
//   d = sigmoid(X @ T^T); leaf probs = depth-10 path products;
//   out = softmax(probs @ L)
//
// Round-8 insight: B fragments are WAVE-PRIVATE in both GEMMs (each wave owns
// a 64-col output strip -> reads only its own B rows). So B skips LDS
// entirely: per-lane global_load_dwordx4 -> registers (L2-resident 2 MiB
// operand). LDS stages only A (shared across waves), double-buffered, BK=32,
// one barrier + one counted vm-gate per K-step. gemm1: b reg-double-buffered
// (unroll-2, static names). gemm2sm (fused softmax): b single-buffered to fit
// 128 regs x 16 waves (4 waves/SIMD). MFMA order unchanged -> absmax canary.
// ---------------------------------------------------------------------------

typedef unsigned short u16;
typedef _Float16 f16;
typedef _Float16 f16x8 __attribute__((ext_vector_type(8)));
typedef float f32x4 __attribute__((ext_vector_type(4)));

#define BATCH 32768
#define DIM   1024
#define NPAD  1024

#define WAIT_VM(N) asm volatile("s_waitcnt vmcnt(" #N ")" ::: "memory")
#define BARRIER()  asm volatile("s_barrier" ::: "memory")

// ---- f16 helpers ----
__device__ __forceinline__ u16 f2h(float f) {
    union { f16 h; u16 u; } v; v.h = (f16)f; return v.u;
}
__device__ __forceinline__ float h2f(u16 u) {
    union { u16 u; f16 h; } v; v.u = u; return (float)v.h;
}

// ---- async global->LDS (dest = wave-uniform base + lane*size) ----
__device__ __forceinline__ void gl16(const u16* g, char* l) {
    __builtin_amdgcn_global_load_lds(
        (const __attribute__((address_space(1))) unsigned int*)g,
        (__attribute__((address_space(3))) unsigned int*)l, 16, 0, 0);
}
__device__ __forceinline__ void gl4(const u16* g, char* l) {
    __builtin_amdgcn_global_load_lds(
        (const __attribute__((address_space(1))) unsigned int*)g,
        (__attribute__((address_space(3))) unsigned int*)l, 4, 0, 0);
}

#define MFMA16(a, b, c) __builtin_amdgcn_mfma_f32_16x16x32_f16(a, b, c, 0, 0, 0)

// ---------------------------------------------------------------------------
// prep kernels (frozen)
// ---------------------------------------------------------------------------
__global__ __launch_bounds__(256) void prep_x(const float4* __restrict__ x4,
                                              u16* __restrict__ xh, int n4) {
    int stride = gridDim.x * blockDim.x;
    for (int i = blockIdx.x * blockDim.x + threadIdx.x; i < n4; i += stride) {
        float4 v = x4[i];
        *(ushort4*)&xh[(size_t)i * 4] =
            make_ushort4(f2h(v.x), f2h(v.y), f2h(v.z), f2h(v.w));
    }
}

__global__ __launch_bounds__(256) void prep_t(const float* __restrict__ t,
                                              u16* __restrict__ th) {
    int i = blockIdx.x * 256 + threadIdx.x;
    int node = i >> 10;
    float v = (node < 1023) ? t[i] : 0.0f;
    th[i] = f2h(v);
}

__global__ __launch_bounds__(256) void prep_lt(const float* __restrict__ L,
                                               u16* __restrict__ LT) {
    __shared__ float tile[32][33];
    int bx = blockIdx.x, by = blockIdx.y;
    int tx = threadIdx.x & 31, ty = threadIdx.x >> 5;
#pragma unroll
    for (int r = 0; r < 4; r++)
        tile[ty + 8 * r][tx] = L[(size_t)(by * 32 + ty + 8 * r) * 1024 + bx * 32 + tx];
    __syncthreads();
#pragma unroll
    for (int r = 0; r < 4; r++)
        LT[(size_t)(bx * 32 + ty + 8 * r) * 1024 + by * 32 + tx] =
            f2h(tile[tx][ty + 8 * r]);
}

// bijective XCD swizzle: 512 blocks, 64 per XCD.
__device__ __forceinline__ void block_map(int bid, int& rb, int& cb) {
    int lid = (bid & 7) * 64 + (bid >> 3);
    rb = (lid >> 2) << 8;
    cb = (lid & 3) << 8;
}

// ---------------------------------------------------------------------------
// GEMM1: d = sigmoid(X @ T^T) -> dval f16.
// 256x256 tile, 8 waves (wm=wid>>2 owns rows wm*128+[0,128); wn=wid&3 owns
// cols wn*64+[0,64)). BK=32, K=1024 (32 steps). A (X) staged to LDS 16KB
// dbuf slots (row-XOR swizzle key=(row&3) on 16B slots, pre-swizzled source);
// B (Th) loaded per-lane to registers, double-buffered via unroll-2.
// Per step: stage A(kt+1) [2x gl16] ; load b(kt+1) [4x dwordx4] ; ds_read
// a[8]; 32 MFMA with b(kt); vm(4) [A landed, b in flight]; barrier.
// ---------------------------------------------------------------------------
__global__ __launch_bounds__(512, 2) void gemm1_8p(
    const u16* __restrict__ Xh, const u16* __restrict__ Th,
    u16* __restrict__ dval)
{
    __shared__ __align__(16) char lds[32768];
    const int t = threadIdx.x, wid = t >> 6, lane = t & 63;
    const int wm = wid >> 2, wn = wid & 3;
    const int mr = lane & 15, kg = lane >> 4;
    int rb, cb;
    block_map(blockIdx.x, rb, cb);

    // A staging source (pre-swizzled so linear dest + XOR'd read match):
    // thread t -> slot t: row = t>>2 (64B rows), 16B-chunk c = t&3,
    // global k-chunk = c ^ (row&3). Second gl16 covers row+128.
    {
    }
    const unsigned arow = (unsigned)(t >> 2);
    const unsigned sA0 = (unsigned)(rb + (int)arow) * 1024u +
                         8u * (unsigned)((t & 3) ^ ((int)arow & 3));

    // a ds_read offsets: row = wm*128 + m*16 + mr; key = (mr&3)<<4
    unsigned offA[8];
#pragma unroll
    for (int m = 0; m < 8; ++m) {
        unsigned row = (unsigned)(wm * 128 + m * 16 + mr);
        offA[m] = row * 64u + (((unsigned)kg << 4) ^ (((unsigned)(mr & 3)) << 4));
    }

    // b global bases (u16 index): col row_b = cb + wn*64 + n*16 + mr
    const u16* bbase[4];
#pragma unroll
    for (int n = 0; n < 4; ++n)
        bbase[n] = Th + (size_t)((unsigned)(cb + wn * 64 + n * 16 + mr) * 1024u
                                 + (unsigned)kg * 8u);

    f32x4 acc[8][4];
#pragma unroll
    for (int m = 0; m < 8; ++m)
#pragma unroll
        for (int n = 0; n < 4; ++n) acc[m][n] = (f32x4){0.f, 0.f, 0.f, 0.f};

    auto stgA = [&](int kt) {
        char* dst = lds + (kt & 1) * 16384 + t * 16;
        const u16* g = Xh + sA0 + (unsigned)kt * 32u;
        gl16(g, dst);
        gl16(g + 131072u, dst + 8192);   // rows +128
    };

    f16x8 bA[4], bB[4];

    // prologue: stage A(0); load b(0) into bA; drain A (b stays in flight)
    stgA(0);
#pragma unroll
    for (int n = 0; n < 4; ++n) bA[n] = *(const f16x8*)(bbase[n]);
    WAIT_VM(4);
    BARRIER();

    // one K-step: consume bu = b(kt), prefetch bl = b(kt+1)
    auto step = [&](int kt, f16x8 (&bu)[4], f16x8 (&bl)[4]) {
        if (kt + 1 < 32) stgA(kt + 1);
        if (kt + 1 < 32) {
#pragma unroll
            for (int n = 0; n < 4; ++n)
                bl[n] = *(const f16x8*)(bbase[n] + (unsigned)(kt + 1) * 32u);
        }
        char* LA = lds + (kt & 1) * 16384;
        f16x8 a[8];
#pragma unroll
        for (int m = 0; m < 8; ++m) a[m] = *(const f16x8*)(LA + offA[m]);
        __builtin_amdgcn_s_setprio(1);
#pragma unroll
        for (int m = 0; m < 8; ++m)
#pragma unroll
            for (int n = 0; n < 4; ++n)
                acc[m][n] = MFMA16(a[m], bu[n], acc[m][n]);
        __builtin_amdgcn_s_setprio(0);
        if (kt + 1 < 32) {
            WAIT_VM(4);   // A(kt+1) landed; b(kt+1) still in flight
            BARRIER();
        }
    };

#pragma unroll 1
    for (int kt2 = 0; kt2 < 16; ++kt2) {
        step(2 * kt2, bA, bB);
        step(2 * kt2 + 1, bB, bA);
    }

    // epilogue: sigmoid -> d f16
    const int fq = kg * 4;
#pragma unroll
    for (int m = 0; m < 8; ++m)
#pragma unroll
        for (int j = 0; j < 4; ++j) {
            int grow = rb + wm * 128 + m * 16 + fq + j;
#pragma unroll
            for (int n = 0; n < 4; ++n) {
                int gcol = cb + wn * 64 + n * 16 + mr;
                float s = acc[m][n][j];
                float d = 1.0f / (1.0f + __expf(-s));
                dval[(size_t)grow * NPAD + gcol] = f2h(d);
            }
        }
}

// ---------------------------------------------------------------------------
// tree expansion (frozen): one wave per row; lane l owns leaves l*16..l*16+15
// ---------------------------------------------------------------------------
__global__ __launch_bounds__(256) void probs_kernel(const u16* __restrict__ dval,
                                                    u16* __restrict__ probs) {
    const int t = threadIdx.x, w = t >> 6, l = t & 63;
    const int row = (blockIdx.x << 2) + w;
    const u16* dp = dval + (size_t)row * NPAD;

    float prod = 1.0f;
#pragma unroll
    for (int lev = 0; lev < 6; lev++) {
        int node = (1 << lev) - 1 + (l >> (6 - lev));
        int bit  = (l >> (5 - lev)) & 1;
        float v = h2f(dp[node]);
        prod *= bit ? (1.0f - v) : v;
    }
    float d6 = h2f(dp[63 + l]);
    float d7[2], d8[4], d9[8];
#pragma unroll
    for (int j = 0; j < 2; j++) d7[j] = h2f(dp[127 + 2 * l + j]);
#pragma unroll
    for (int j = 0; j < 4; j++) d8[j] = h2f(dp[255 + 4 * l + j]);
#pragma unroll
    for (int j = 0; j < 8; j++) d9[j] = h2f(dp[511 + 8 * l + j]);

    u16 outv[16];
#pragma unroll
    for (int j = 0; j < 16; j++) {
        float f6 = (j >> 3) ? (1.0f - d6) : d6;
        float v7 = d7[j >> 3];  float f7 = ((j >> 2) & 1) ? (1.0f - v7) : v7;
        float v8 = d8[j >> 2];  float f8 = ((j >> 1) & 1) ? (1.0f - v8) : v8;
        float v9 = d9[j >> 1];  float f9 = (j & 1) ? (1.0f - v9) : v9;
        outv[j] = f2h(prod * f6 * f7 * f8 * f9);
    }
    ushort4* po = (ushort4*)(probs + (size_t)row * 1024 + (l << 4));
#pragma unroll
    for (int q = 0; q < 4; q++)
        po[q] = make_ushort4(outv[4 * q], outv[4 * q + 1], outv[4 * q + 2], outv[4 * q + 3]);
}

// ---------------------------------------------------------------------------
// FUSED GEMM2 + SOFTMAX, round 8: B (LT) per-lane to registers (single-buf),
// A (probs) via LDS 4KB dbuf (gl4, round-7 swizzle pair). Block = 64 full
// rows, 1024 threads / 16 waves; wave wid owns cols wid*64: acc[4][4].
// Per step: stage A(kt+1) [1 gl4]; load b(kt) [4x dwordx4]; ds_read a[4];
// 16 MFMA; vm(0) [A landed]; barrier. LDS total 8KB (reused by softmax).
// ---------------------------------------------------------------------------
__global__ __launch_bounds__(1024, 1) void gemm2sm(
    const u16* __restrict__ P, const u16* __restrict__ LT,
    float* __restrict__ out)
{
    __shared__ __align__(16) char lds[8192];
    const int t = threadIdx.x, wid = t >> 6, lane = t & 63;
    const int mr = lane & 15, kg = lane >> 4;
    const int rb = blockIdx.x * 64;

    // A staging source (round-7 pair: key = (row>>1)&3 on 16B slots)
    const int arow = t >> 4;
    const unsigned akoff =
        (unsigned)(((((t >> 2) & 3) ^ ((arow >> 1) & 3)) << 3) + ((t & 3) << 1));

    // a ds_read offsets: row = m*16 + mr; key = (row>>1)&3
    unsigned offA[4];
#pragma unroll
    for (int m = 0; m < 4; ++m) {
        int row = m * 16 + mr;
        offA[m] = (unsigned)(row * 64) + ((unsigned)(kg ^ ((row >> 1) & 3)) << 4);
    }

    // b global bases: row_b = wid*64 + n*16 + mr
    const u16* bbase[4];
#pragma unroll
    for (int n = 0; n < 4; ++n)
        bbase[n] = LT + (size_t)((unsigned)(wid * 64 + n * 16 + mr) * 1024u
                                 + (unsigned)kg * 8u);

    f32x4 acc[4][4];
#pragma unroll
    for (int m = 0; m < 4; ++m)
#pragma unroll
        for (int n = 0; n < 4; ++n) acc[m][n] = (f32x4){0.f, 0.f, 0.f, 0.f};

    auto stgA = [&](int kt) {
        char* sa = lds + (kt & 1) * 4096;
        const u16* asrc = P + (size_t)(rb + arow) * 1024 + (unsigned)kt * 32u + akoff;
        gl4(asrc, sa + t * 4);
    };

    stgA(0);
    WAIT_VM(0);
    BARRIER();

#pragma unroll 1
    for (int kt = 0; kt < 32; ++kt) {
        if (kt + 1 < 32) stgA(kt + 1);
        f16x8 b[4];
#pragma unroll
        for (int n = 0; n < 4; ++n)
            b[n] = *(const f16x8*)(bbase[n] + (unsigned)kt * 32u);
        char* sa = lds + (kt & 1) * 4096;
        f16x8 a[4];
#pragma unroll
        for (int m = 0; m < 4; ++m) a[m] = *(const f16x8*)(sa + offA[m]);
        __builtin_amdgcn_s_setprio(1);
#pragma unroll
        for (int m = 0; m < 4; ++m)
#pragma unroll
            for (int n = 0; n < 4; ++n)
                acc[m][n] = MFMA16(a[m], b[n], acc[m][n]);
        __builtin_amdgcn_s_setprio(0);
        if (kt + 1 < 32) {
            WAIT_VM(0);   // A(kt+1) landed (issued at step start; b drained by MFMA)
            BARRIER();
        }
    }

    // ---------------- in-register softmax over full rows ----------------
    // thread rows: r(m,j) = m*16 + kg*4 + j; cols: wid*64 + n*16 + mr
    float* red  = (float*)lds;           // [64][16] max  (slot 0 region)
    float* red2 = (float*)(lds + 4096);  // [64][16] sum  (slot 1 region)
    const int fq = kg * 4;

    float mx[4][4];
#pragma unroll
    for (int m = 0; m < 4; ++m)
#pragma unroll
        for (int j = 0; j < 4; ++j) {
            float v = acc[m][0][j];
#pragma unroll
            for (int n = 1; n < 4; ++n) v = fmaxf(v, acc[m][n][j]);
#pragma unroll
            for (int off = 1; off < 16; off <<= 1)
                v = fmaxf(v, __shfl_xor(v, off));
            mx[m][j] = v;
        }
    if (mr == 0) {
#pragma unroll
        for (int m = 0; m < 4; ++m)
#pragma unroll
            for (int j = 0; j < 4; ++j)
                red[(m * 16 + fq + j) * 16 + wid] = mx[m][j];
    }
    __syncthreads();
    if (t < 64) {
        float v = red[t * 16];
#pragma unroll
        for (int w = 1; w < 16; ++w) v = fmaxf(v, red[t * 16 + w]);
        red[t * 16] = v;
    }
    __syncthreads();

    float sm[4][4];
#pragma unroll
    for (int m = 0; m < 4; ++m)
#pragma unroll
        for (int j = 0; j < 4; ++j) {
            float M = red[(m * 16 + fq + j) * 16];
            float s = 0.f;
#pragma unroll
            for (int n = 0; n < 4; ++n) {
                float e = __expf(acc[m][n][j] - M);
                acc[m][n][j] = e;
                s += e;
            }
#pragma unroll
            for (int off = 1; off < 16; off <<= 1)
                s += __shfl_xor(s, off);
            sm[m][j] = s;
        }
    if (mr == 0) {
#pragma unroll
        for (int m = 0; m < 4; ++m)
#pragma unroll
            for (int j = 0; j < 4; ++j)
                red2[(m * 16 + fq + j) * 16 + wid] = sm[m][j];
    }
    __syncthreads();
    if (t < 64) {
        float v = 0.f;
#pragma unroll
        for (int w = 0; w < 16; ++w) v += red2[t * 16 + w];
        red2[t * 16] = 1.0f / v;
    }
    __syncthreads();

#pragma unroll
    for (int m = 0; m < 4; ++m)
#pragma unroll
        for (int j = 0; j < 4; ++j) {
            int grow = rb + m * 16 + fq + j;
            float inv = red2[(m * 16 + fq + j) * 16];
#pragma unroll
            for (int n = 0; n < 4; ++n) {
                int gcol = wid * 64 + n * 16 + mr;
                out[(size_t)grow * 1024 + gcol] = acc[m][n][j] * inv;
            }
        }
}

// ---------------------------------------------------------------------------
extern "C" void kernel_launch(void* const* d_in, const int* in_sizes, int n_in,
                              void* d_out, int out_size, void* d_ws, size_t ws_size,
                              hipStream_t stream) {
    const float* x  = (const float*)d_in[0];
    const float* ft = (const float*)d_in[1];
    const float* lp = (const float*)d_in[2];
    float* out = (float*)d_out;
    char* ws = (char*)d_ws;

    // ws layout: Xh 64Mi | Th 2Mi | LT 2Mi | dval 64Mi | probs 64Mi
    u16* Xh = (u16*)ws;
    u16* Th = (u16*)(ws + (size_t)67108864);
    u16* LT = Th + (size_t)NPAD * DIM;
    u16* dval = (u16*)(ws + (size_t)67108864 + 2 * 2097152);
    u16* probs = dval + (size_t)BATCH * NPAD;

    prep_x<<<4096, 256, 0, stream>>>((const float4*)x, Xh, BATCH * DIM / 4);
    prep_t<<<4096, 256, 0, stream>>>(ft, Th);
    prep_lt<<<dim3(32, 32), 256, 0, stream>>>(lp, LT);
    gemm1_8p<<<512, 512, 0, stream>>>(Xh, Th, dval);
    probs_kernel<<<8192, 256, 0, stream>>>(dval, probs);
    gemm2sm<<<512, 1024, 0, stream>>>(probs, LT, out);
}

// Round 9
// 307.780 us; speedup vs baseline: 1.1405x; 1.1405x over previous
//
#include <hip/hip_runtime.h>

// ---------------------------------------------------------------------------
// Soft decision tree forward (all-f16 pipeline), round 9.
//   d = sigmoid(X @ T^T); leaf probs = depth-10 path products;
//   out = softmax(probs @ L)
//
// gemm1/probs/prep: reverted to round-6 state (best known).
// gemm2sm: fused gemm2+softmax with B (LT) kept in REGISTERS with a
// one-step prefetch double-buffer (fixes round-8's synchronous b-loads).
// Waves own disjoint 64-col strips -> no B duplication; A (probs) staged
// via 4KB LDS dbuf (gl4). One barrier + counted vm(4) per K-step.
// ---------------------------------------------------------------------------

typedef unsigned short u16;
typedef _Float16 f16;
typedef _Float16 f16x8 __attribute__((ext_vector_type(8)));
typedef float f32x4 __attribute__((ext_vector_type(4)));

#define BATCH 32768
#define DIM   1024
#define NPAD  1024

#define WAIT_VM(N) asm volatile("s_waitcnt vmcnt(" #N ")" ::: "memory")
#define BARRIER()  asm volatile("s_barrier" ::: "memory")

// ---- f16 helpers ----
__device__ __forceinline__ u16 f2h(float f) {
    union { f16 h; u16 u; } v; v.h = (f16)f; return v.u;
}
__device__ __forceinline__ float h2f(u16 u) {
    union { u16 u; f16 h; } v; v.u = u; return (float)v.h;
}

// ---- async global->LDS (dest = wave-uniform base + lane*size) ----
__device__ __forceinline__ void gl16(const u16* g, char* l) {
    __builtin_amdgcn_global_load_lds(
        (const __attribute__((address_space(1))) unsigned int*)g,
        (__attribute__((address_space(3))) unsigned int*)l, 16, 0, 0);
}
__device__ __forceinline__ void gl4(const u16* g, char* l) {
    __builtin_amdgcn_global_load_lds(
        (const __attribute__((address_space(1))) unsigned int*)g,
        (__attribute__((address_space(3))) unsigned int*)l, 4, 0, 0);
}

#define MFMA16(a, b, c) __builtin_amdgcn_mfma_f32_16x16x32_f16(a, b, c, 0, 0, 0)

// ---------------------------------------------------------------------------
// prep kernels (frozen)
// ---------------------------------------------------------------------------
__global__ __launch_bounds__(256) void prep_x(const float4* __restrict__ x4,
                                              u16* __restrict__ xh, int n4) {
    int stride = gridDim.x * blockDim.x;
    for (int i = blockIdx.x * blockDim.x + threadIdx.x; i < n4; i += stride) {
        float4 v = x4[i];
        *(ushort4*)&xh[(size_t)i * 4] =
            make_ushort4(f2h(v.x), f2h(v.y), f2h(v.z), f2h(v.w));
    }
}

__global__ __launch_bounds__(256) void prep_t(const float* __restrict__ t,
                                              u16* __restrict__ th) {
    int i = blockIdx.x * 256 + threadIdx.x;
    int node = i >> 10;
    float v = (node < 1023) ? t[i] : 0.0f;
    th[i] = f2h(v);
}

__global__ __launch_bounds__(256) void prep_lt(const float* __restrict__ L,
                                               u16* __restrict__ LT) {
    __shared__ float tile[32][33];
    int bx = blockIdx.x, by = blockIdx.y;
    int tx = threadIdx.x & 31, ty = threadIdx.x >> 5;
#pragma unroll
    for (int r = 0; r < 4; r++)
        tile[ty + 8 * r][tx] = L[(size_t)(by * 32 + ty + 8 * r) * 1024 + bx * 32 + tx];
    __syncthreads();
#pragma unroll
    for (int r = 0; r < 4; r++)
        LT[(size_t)(bx * 32 + ty + 8 * r) * 1024 + by * 32 + tx] =
            f2h(tile[tx][ty + 8 * r]);
}

// bijective XCD swizzle: 512 blocks, 64 per XCD.
__device__ __forceinline__ void block_map(int bid, int& rb, int& cb) {
    int lid = (bid & 7) * 64 + (bid >> 3);
    rb = (lid >> 2) << 8;
    cb = (lid & 3) << 8;
}

// ---------------------------------------------------------------------------
// GEMM1 core (round-5 4-phase 256x256 pipeline, frozen)
// ---------------------------------------------------------------------------
template <int NT>
__device__ __forceinline__ void gemm_core8(const u16* __restrict__ Ap,
                                           const u16* __restrict__ Bp,
                                           int rb, int cb, char* lds,
                                           f32x4 acc[8][4])
{
    const int t = threadIdx.x, wid = t >> 6, lane = t & 63;
    const int wm = wid >> 2, wn = wid & 3;
    const int mr = lane & 15, kg = lane >> 4;

    const int tr = t >> 3;
    const unsigned koff = 8u * ((unsigned)((t & 7) ^ (tr & 7)));
    const unsigned sAlo = (unsigned)(rb + tr) * 1024u + koff;
    const unsigned sAhi = sAlo + 131072u;
    const unsigned sBlo = (unsigned)(cb + tr) * 1024u + koff;
    const unsigned sBhi = sBlo + 131072u;

    const unsigned key = (unsigned)(mr & 7) << 4;
    const unsigned e0 = (unsigned)mr * 128u + (((unsigned)kg * 16u) ^ key);
    const unsigned e1 = (unsigned)mr * 128u + ((64u + (unsigned)kg * 16u) ^ key);
    const unsigned bbase = (unsigned)(wn & 1) * 8192u;
    const unsigned bhalf = (unsigned)(wn >> 1) * 16384u;

#pragma unroll
    for (int m = 0; m < 8; ++m)
#pragma unroll
        for (int n = 0; n < 4; ++n) acc[m][n] = (f32x4){0.f, 0.f, 0.f, 0.f};

    auto stg = [&](int kt, unsigned srcb, const u16* G, int region, int halfo) {
        char* dst = lds + region + (kt & 1) * 32768 + halfo + t * 16;
        const u16* g = G + srcb + (unsigned)kt * 64u;
        gl16(g, dst);
        gl16(g + 65536, dst + 8192);
    };

    stg(0, sAlo, Ap, 0, 0);      stg(0, sAhi, Ap, 0, 16384);
    stg(0, sBlo, Bp, 65536, 0);  stg(0, sBhi, Bp, 65536, 16384);
    stg(1, sAlo, Ap, 0, 0);      stg(1, sAhi, Ap, 0, 16384);
    stg(1, sBlo, Bp, 65536, 0);  stg(1, sBhi, Bp, 65536, 16384);
    WAIT_VM(8);
    BARRIER();

    f16x8 a[4][2], b01[2][2], b23[2][2];

    {
        char* LB = lds + 65536 + bhalf;
#pragma unroll
        for (int n = 0; n < 2; ++n) {
            b01[n][0] = *(const f16x8*)(LB + bbase + n * 2048 + e0);
            b01[n][1] = *(const f16x8*)(LB + bbase + n * 2048 + e1);
        }
    }

#pragma unroll 1
    for (int kt = 0; kt < NT; ++kt) {
        char* LA = lds + (kt & 1) * 32768 + wm * 16384;
        char* LB = lds + 65536 + (kt & 1) * 32768 + bhalf;

        // P1: read a0-3; stage A-lo(t+1); MFMA m0-3 x b01
#pragma unroll
        for (int i = 0; i < 4; ++i) {
            a[i][0] = *(const f16x8*)(LA + i * 2048 + e0);
            a[i][1] = *(const f16x8*)(LA + i * 2048 + e1);
        }
        if (kt + 1 < NT) stg(kt + 1, sAlo, Ap, 0, 0);
        BARRIER();
        __builtin_amdgcn_s_setprio(1);
#pragma unroll
        for (int i = 0; i < 4; ++i)
#pragma unroll
            for (int n = 0; n < 2; ++n) {
                acc[i][n] = MFMA16(a[i][0], b01[n][0], acc[i][n]);
                acc[i][n] = MFMA16(a[i][1], b01[n][1], acc[i][n]);
            }
        __builtin_amdgcn_s_setprio(0);
        BARRIER();

        // P2: read b23; stage A-hi(t+1); MFMA m0-3 x b23
#pragma unroll
        for (int n = 0; n < 2; ++n) {
            b23[n][0] = *(const f16x8*)(LB + bbase + (2 + n) * 2048 + e0);
            b23[n][1] = *(const f16x8*)(LB + bbase + (2 + n) * 2048 + e1);
        }
        if (kt + 1 < NT) stg(kt + 1, sAhi, Ap, 0, 16384);
        BARRIER();
        __builtin_amdgcn_s_setprio(1);
#pragma unroll
        for (int i = 0; i < 4; ++i)
#pragma unroll
            for (int n = 0; n < 2; ++n) {
                acc[i][2 + n] = MFMA16(a[i][0], b23[n][0], acc[i][2 + n]);
                acc[i][2 + n] = MFMA16(a[i][1], b23[n][1], acc[i][2 + n]);
            }
        __builtin_amdgcn_s_setprio(0);
        BARRIER();

        // P3: read a4-7; stage B-lo(t+2); MFMA m4-7 x b23
#pragma unroll
        for (int i = 0; i < 4; ++i) {
            a[i][0] = *(const f16x8*)(LA + (4 + i) * 2048 + e0);
            a[i][1] = *(const f16x8*)(LA + (4 + i) * 2048 + e1);
        }
        if (kt + 2 < NT) stg(kt + 2, sBlo, Bp, 65536, 0);
        BARRIER();
        __builtin_amdgcn_s_setprio(1);
#pragma unroll
        for (int i = 0; i < 4; ++i)
#pragma unroll
            for (int n = 0; n < 2; ++n) {
                acc[4 + i][2 + n] = MFMA16(a[i][0], b23[n][0], acc[4 + i][2 + n]);
                acc[4 + i][2 + n] = MFMA16(a[i][1], b23[n][1], acc[4 + i][2 + n]);
            }
        __builtin_amdgcn_s_setprio(0);
        BARRIER();

        // P4: stage B-hi(t+2); MFMA m4-7 x b01; gates; read b01(t+1)
        if (kt + 2 < NT) stg(kt + 2, sBhi, Bp, 65536, 16384);
        BARRIER();
        __builtin_amdgcn_s_setprio(1);
#pragma unroll
        for (int i = 0; i < 4; ++i)
#pragma unroll
            for (int n = 0; n < 2; ++n) {
                acc[4 + i][n] = MFMA16(a[i][0], b01[n][0], acc[4 + i][n]);
                acc[4 + i][n] = MFMA16(a[i][1], b01[n][1], acc[4 + i][n]);
            }
        __builtin_amdgcn_s_setprio(0);
        if (kt + 1 < NT) {
            if (kt + 2 < NT) { WAIT_VM(8); } else { WAIT_VM(4); }
            char* LB2 = lds + 65536 + ((kt + 1) & 1) * 32768 + bhalf;
#pragma unroll
            for (int n = 0; n < 2; ++n) {
                b01[n][0] = *(const f16x8*)(LB2 + bbase + n * 2048 + e0);
                b01[n][1] = *(const f16x8*)(LB2 + bbase + n * 2048 + e1);
            }
            if (kt + 2 < NT) { WAIT_VM(4); } else { WAIT_VM(0); }
        }
        BARRIER();
    }
}

// ---------------------------------------------------------------------------
// GEMM1: d = sigmoid(X @ T^T), store d f16 (scalar)
// ---------------------------------------------------------------------------
__global__ __launch_bounds__(512, 2) void gemm1_8p(
    const u16* __restrict__ Xh, const u16* __restrict__ Th,
    u16* __restrict__ dval)
{
    __shared__ __align__(16) char lds[131072];
    int rb, cb;
    block_map(blockIdx.x, rb, cb);
    f32x4 acc[8][4];
    gemm_core8<16>(Xh, Th, rb, cb, lds, acc);

    const int lane = threadIdx.x & 63, wid = threadIdx.x >> 6;
    const int wm = wid >> 2, wn = wid & 3;
    const int mr = lane & 15, fq = (lane >> 4) * 4;
#pragma unroll
    for (int m = 0; m < 8; ++m)
#pragma unroll
        for (int j = 0; j < 4; ++j) {
            int grow = rb + wm * 128 + m * 16 + fq + j;
#pragma unroll
            for (int n = 0; n < 4; ++n) {
                int gcol = cb + wn * 64 + n * 16 + mr;
                float s = acc[m][n][j];
                float d = 1.0f / (1.0f + __expf(-s));
                dval[(size_t)grow * NPAD + gcol] = f2h(d);
            }
        }
}

// ---------------------------------------------------------------------------
// tree expansion (frozen): one wave per row; lane l owns leaves l*16..l*16+15
// ---------------------------------------------------------------------------
__global__ __launch_bounds__(256) void probs_kernel(const u16* __restrict__ dval,
                                                    u16* __restrict__ probs) {
    const int t = threadIdx.x, w = t >> 6, l = t & 63;
    const int row = (blockIdx.x << 2) + w;
    const u16* dp = dval + (size_t)row * NPAD;

    float prod = 1.0f;
#pragma unroll
    for (int lev = 0; lev < 6; lev++) {
        int node = (1 << lev) - 1 + (l >> (6 - lev));
        int bit  = (l >> (5 - lev)) & 1;
        float v = h2f(dp[node]);
        prod *= bit ? (1.0f - v) : v;
    }
    float d6 = h2f(dp[63 + l]);
    float d7[2], d8[4], d9[8];
#pragma unroll
    for (int j = 0; j < 2; j++) d7[j] = h2f(dp[127 + 2 * l + j]);
#pragma unroll
    for (int j = 0; j < 4; j++) d8[j] = h2f(dp[255 + 4 * l + j]);
#pragma unroll
    for (int j = 0; j < 8; j++) d9[j] = h2f(dp[511 + 8 * l + j]);

    u16 outv[16];
#pragma unroll
    for (int j = 0; j < 16; j++) {
        float f6 = (j >> 3) ? (1.0f - d6) : d6;
        float v7 = d7[j >> 3];  float f7 = ((j >> 2) & 1) ? (1.0f - v7) : v7;
        float v8 = d8[j >> 2];  float f8 = ((j >> 1) & 1) ? (1.0f - v8) : v8;
        float v9 = d9[j >> 1];  float f9 = (j & 1) ? (1.0f - v9) : v9;
        outv[j] = f2h(prod * f6 * f7 * f8 * f9);
    }
    ushort4* po = (ushort4*)(probs + (size_t)row * 1024 + (l << 4));
#pragma unroll
    for (int q = 0; q < 4; q++)
        po[q] = make_ushort4(outv[4 * q], outv[4 * q + 1], outv[4 * q + 2], outv[4 * q + 3]);
}

// ---------------------------------------------------------------------------
// FUSED GEMM2 + SOFTMAX, round 9: B (LT) per-lane in REGISTERS with one-step
// prefetch double-buffer (bA/bB, unroll-2). A (probs) via 4KB LDS dbuf (gl4).
// Block = 64 full rows, 1024 threads / 16 waves; wave wid owns cols wid*64
// (disjoint strips -> no B duplication). Per step kt:
//   stgA(kt+1) [1 gl4] ; issue b(kt+1) [4x dwordx4] ; ds_read a[4] ;
//   16 MFMA with b(kt) [compiler vmcnt(5) leaves new loads in flight] ;
//   vm(4) [A landed, b(kt+1) in flight] ; barrier.
// Epilogue: in-register softmax (16-lane shfl + LDS merge), final f32 write.
// ---------------------------------------------------------------------------
__global__ __launch_bounds__(1024, 1) void gemm2sm(
    const u16* __restrict__ P, const u16* __restrict__ LT,
    float* __restrict__ out)
{
    __shared__ __align__(16) char lds[8192];
    const int t = threadIdx.x, wid = t >> 6, lane = t & 63;
    const int mr = lane & 15, kg = lane >> 4;
    const int rb = blockIdx.x * 64;

    // A staging source (key = (row>>1)&3 on 16B slots)
    const int arow = t >> 4;
    const unsigned akoff =
        (unsigned)(((((t >> 2) & 3) ^ ((arow >> 1) & 3)) << 3) + ((t & 3) << 1));

    // a ds_read offsets: row = m*16 + mr; key = (row>>1)&3
    unsigned offA[4];
#pragma unroll
    for (int m = 0; m < 4; ++m) {
        int row = m * 16 + mr;
        offA[m] = (unsigned)(row * 64) + ((unsigned)(kg ^ ((row >> 1) & 3)) << 4);
    }

    // b global bases: row_b = wid*64 + n*16 + mr
    const u16* bbase[4];
#pragma unroll
    for (int n = 0; n < 4; ++n)
        bbase[n] = LT + (size_t)((unsigned)(wid * 64 + n * 16 + mr) * 1024u
                                 + (unsigned)kg * 8u);

    f32x4 acc[4][4];
#pragma unroll
    for (int m = 0; m < 4; ++m)
#pragma unroll
        for (int n = 0; n < 4; ++n) acc[m][n] = (f32x4){0.f, 0.f, 0.f, 0.f};

    auto stgA = [&](int kt) {
        char* sa = lds + (kt & 1) * 4096;
        const u16* asrc = P + (size_t)(rb + arow) * 1024 + (unsigned)kt * 32u + akoff;
        gl4(asrc, sa + t * 4);
    };

    f16x8 bA[4], bB[4];

    // prologue: stage A(0); load b(0); gate A only (b stays in flight)
    stgA(0);
#pragma unroll
    for (int n = 0; n < 4; ++n) bA[n] = *(const f16x8*)(bbase[n]);
    WAIT_VM(4);
    BARRIER();

    auto step = [&](int kt, f16x8 (&bu)[4], f16x8 (&bl)[4]) {
        if (kt + 1 < 32) {
            stgA(kt + 1);
#pragma unroll
            for (int n = 0; n < 4; ++n)
                bl[n] = *(const f16x8*)(bbase[n] + (unsigned)(kt + 1) * 32u);
        }
        char* sa = lds + (kt & 1) * 4096;
        f16x8 a[4];
#pragma unroll
        for (int m = 0; m < 4; ++m) a[m] = *(const f16x8*)(sa + offA[m]);
        __builtin_amdgcn_s_setprio(1);
#pragma unroll
        for (int m = 0; m < 4; ++m)
#pragma unroll
            for (int n = 0; n < 4; ++n)
                acc[m][n] = MFMA16(a[m], bu[n], acc[m][n]);
        __builtin_amdgcn_s_setprio(0);
        if (kt + 1 < 32) {
            WAIT_VM(4);   // A(kt+1) landed; b(kt+1) still in flight
            BARRIER();
        }
    };

#pragma unroll 1
    for (int k2 = 0; k2 < 16; ++k2) {
        step(2 * k2, bA, bB);
        step(2 * k2 + 1, bB, bA);
    }

    // ---------------- in-register softmax over full rows ----------------
    // thread rows: r(m,j) = m*16 + kg*4 + j; cols: wid*64 + n*16 + mr
    float* red  = (float*)lds;           // [64][16] max  (slot 0 region)
    float* red2 = (float*)(lds + 4096);  // [64][16] sum  (slot 1 region)
    const int fq = kg * 4;

    float mx[4][4];
#pragma unroll
    for (int m = 0; m < 4; ++m)
#pragma unroll
        for (int j = 0; j < 4; ++j) {
            float v = acc[m][0][j];
#pragma unroll
            for (int n = 1; n < 4; ++n) v = fmaxf(v, acc[m][n][j]);
#pragma unroll
            for (int off = 1; off < 16; off <<= 1)
                v = fmaxf(v, __shfl_xor(v, off));
            mx[m][j] = v;
        }
    if (mr == 0) {
#pragma unroll
        for (int m = 0; m < 4; ++m)
#pragma unroll
            for (int j = 0; j < 4; ++j)
                red[(m * 16 + fq + j) * 16 + wid] = mx[m][j];
    }
    __syncthreads();
    if (t < 64) {
        float v = red[t * 16];
#pragma unroll
        for (int w = 1; w < 16; ++w) v = fmaxf(v, red[t * 16 + w]);
        red[t * 16] = v;
    }
    __syncthreads();

    float sm[4][4];
#pragma unroll
    for (int m = 0; m < 4; ++m)
#pragma unroll
        for (int j = 0; j < 4; ++j) {
            float M = red[(m * 16 + fq + j) * 16];
            float s = 0.f;
#pragma unroll
            for (int n = 0; n < 4; ++n) {
                float e = __expf(acc[m][n][j] - M);
                acc[m][n][j] = e;
                s += e;
            }
#pragma unroll
            for (int off = 1; off < 16; off <<= 1)
                s += __shfl_xor(s, off);
            sm[m][j] = s;
        }
    if (mr == 0) {
#pragma unroll
        for (int m = 0; m < 4; ++m)
#pragma unroll
            for (int j = 0; j < 4; ++j)
                red2[(m * 16 + fq + j) * 16 + wid] = sm[m][j];
    }
    __syncthreads();
    if (t < 64) {
        float v = 0.f;
#pragma unroll
        for (int w = 0; w < 16; ++w) v += red2[t * 16 + w];
        red2[t * 16] = 1.0f / v;
    }
    __syncthreads();

#pragma unroll
    for (int m = 0; m < 4; ++m)
#pragma unroll
        for (int j = 0; j < 4; ++j) {
            int grow = rb + m * 16 + fq + j;
            float inv = red2[(m * 16 + fq + j) * 16];
#pragma unroll
            for (int n = 0; n < 4; ++n) {
                int gcol = wid * 64 + n * 16 + mr;
                out[(size_t)grow * 1024 + gcol] = acc[m][n][j] * inv;
            }
        }
}

// ---------------------------------------------------------------------------
extern "C" void kernel_launch(void* const* d_in, const int* in_sizes, int n_in,
                              void* d_out, int out_size, void* d_ws, size_t ws_size,
                              hipStream_t stream) {
    const float* x  = (const float*)d_in[0];
    const float* ft = (const float*)d_in[1];
    const float* lp = (const float*)d_in[2];
    float* out = (float*)d_out;
    char* ws = (char*)d_ws;

    // ws layout: Xh 64Mi | Th 2Mi | LT 2Mi | dval 64Mi | probs 64Mi
    u16* Xh = (u16*)ws;
    u16* Th = (u16*)(ws + (size_t)67108864);
    u16* LT = Th + (size_t)NPAD * DIM;
    u16* dval = (u16*)(ws + (size_t)67108864 + 2 * 2097152);
    u16* probs = dval + (size_t)BATCH * NPAD;

    prep_x<<<4096, 256, 0, stream>>>((const float4*)x, Xh, BATCH * DIM / 4);
    prep_t<<<4096, 256, 0, stream>>>(ft, Th);
    prep_lt<<<dim3(32, 32), 256, 0, stream>>>(lp, LT);
    gemm1_8p<<<512, 512, 0, stream>>>(Xh, Th, dval);
    probs_kernel<<<8192, 256, 0, stream>>>(dval, probs);
    gemm2sm<<<512, 1024, 0, stream>>>(probs, LT, out);
}

// Round 10
// 255.155 us; speedup vs baseline: 1.3757x; 1.2062x over previous
//
#include <hip/hip_runtime.h>

// ---------------------------------------------------------------------------
// Soft decision tree forward (all-f16 pipeline), round 10.
//   d = sigmoid(X @ T^T); leaf probs = depth-10 path products;
//   out = softmax(probs @ L)
//
// Round-10: gemm2's operands are stored in MFMA-FRAGMENT ORDER by their
// producers (prep_lt packs L; probs_kernel packs leaf probs), so the fused
// gemm2+softmax kernel loads both operands direct-to-register with perfectly
// coalesced wave-contiguous 1KB loads: ZERO LDS / barriers in the K-loop.
// Fragment layout (established, correctness-proven since round 2):
//   frag element (lane = kg*16+mr, j) = Op[row 16-block + mr][kt*32 + kg*8 + j]
//   A pack: Apk[rb64*65536 + kt*2048 + m*512 + lane*8 + j]
//   B pack: Bpk[(b16*32 + kt)*512 + lane*8 + j]
// gemm1 (4-phase 256x256 core), prep_x, prep_t frozen at round-6 state.
// ---------------------------------------------------------------------------

typedef unsigned short u16;
typedef unsigned short u16x8 __attribute__((ext_vector_type(8)));
typedef _Float16 f16;
typedef _Float16 f16x8 __attribute__((ext_vector_type(8)));
typedef float f32x4 __attribute__((ext_vector_type(4)));

#define BATCH 32768
#define DIM   1024
#define NPAD  1024

#define WAIT_VM(N) asm volatile("s_waitcnt vmcnt(" #N ")" ::: "memory")
#define BARRIER()  asm volatile("s_barrier" ::: "memory")

// ---- f16 helpers ----
__device__ __forceinline__ u16 f2h(float f) {
    union { f16 h; u16 u; } v; v.h = (f16)f; return v.u;
}
__device__ __forceinline__ float h2f(u16 u) {
    union { u16 u; f16 h; } v; v.u = u; return (float)v.h;
}

// ---- async global->LDS (dest = wave-uniform base + lane*size) ----
__device__ __forceinline__ void gl16(const u16* g, char* l) {
    __builtin_amdgcn_global_load_lds(
        (const __attribute__((address_space(1))) unsigned int*)g,
        (__attribute__((address_space(3))) unsigned int*)l, 16, 0, 0);
}

#define MFMA16(a, b, c) __builtin_amdgcn_mfma_f32_16x16x32_f16(a, b, c, 0, 0, 0)

// ---------------------------------------------------------------------------
// prep: X f32 -> Xh f16 (frozen)
// ---------------------------------------------------------------------------
__global__ __launch_bounds__(256) void prep_x(const float4* __restrict__ x4,
                                              u16* __restrict__ xh, int n4) {
    int stride = gridDim.x * blockDim.x;
    for (int i = blockIdx.x * blockDim.x + threadIdx.x; i < n4; i += stride) {
        float4 v = x4[i];
        *(ushort4*)&xh[(size_t)i * 4] =
            make_ushort4(f2h(v.x), f2h(v.y), f2h(v.z), f2h(v.w));
    }
}

// ---------------------------------------------------------------------------
// prep: thresholds -> Th f16 [1024][1024], row 1023 = 0 (frozen)
// ---------------------------------------------------------------------------
__global__ __launch_bounds__(256) void prep_t(const float* __restrict__ t,
                                              u16* __restrict__ th) {
    int i = blockIdx.x * 256 + threadIdx.x;
    int node = i >> 10;
    float v = (node < 1023) ? t[i] : 0.0f;
    th[i] = f2h(v);
}

// ---------------------------------------------------------------------------
// prep: L (1024x1024 f32, [leaf][out]) -> Bpk fragment-packed f16.
// Bpk[((b16*32 + kt)*64 + lane)*8 + j] = L[kt*32 + kg*8 + j][b16*16 + mr]
// 1M u16 total; thread handles 4 consecutive u16 (same b16/kt/lane, j0=0|4).
// ---------------------------------------------------------------------------
__global__ __launch_bounds__(256) void prep_lt(const float* __restrict__ L,
                                               u16* __restrict__ Bpk) {
    int o = (blockIdx.x * 256 + threadIdx.x) * 4;
    int b16  = o >> 14;
    int kt   = (o >> 9) & 31;
    int lane = (o >> 3) & 63;
    int j0   = o & 7;
    int mr = lane & 15, kg = lane >> 4;
    int col = b16 * 16 + mr;
    int k0  = kt * 32 + kg * 8 + j0;
    ushort4 v;
    v.x = f2h(L[(size_t)(k0 + 0) * 1024 + col]);
    v.y = f2h(L[(size_t)(k0 + 1) * 1024 + col]);
    v.z = f2h(L[(size_t)(k0 + 2) * 1024 + col]);
    v.w = f2h(L[(size_t)(k0 + 3) * 1024 + col]);
    *(ushort4*)&Bpk[o] = v;
}

// bijective XCD swizzle: 512 blocks, 64 per XCD.
__device__ __forceinline__ void block_map(int bid, int& rb, int& cb) {
    int lid = (bid & 7) * 64 + (bid >> 3);
    rb = (lid >> 2) << 8;
    cb = (lid & 3) << 8;
}

// ---------------------------------------------------------------------------
// GEMM1 core (round-5 4-phase 256x256 pipeline, frozen)
// ---------------------------------------------------------------------------
template <int NT>
__device__ __forceinline__ void gemm_core8(const u16* __restrict__ Ap,
                                           const u16* __restrict__ Bp,
                                           int rb, int cb, char* lds,
                                           f32x4 acc[8][4])
{
    const int t = threadIdx.x, wid = t >> 6, lane = t & 63;
    const int wm = wid >> 2, wn = wid & 3;
    const int mr = lane & 15, kg = lane >> 4;

    const int tr = t >> 3;
    const unsigned koff = 8u * ((unsigned)((t & 7) ^ (tr & 7)));
    const unsigned sAlo = (unsigned)(rb + tr) * 1024u + koff;
    const unsigned sAhi = sAlo + 131072u;
    const unsigned sBlo = (unsigned)(cb + tr) * 1024u + koff;
    const unsigned sBhi = sBlo + 131072u;

    const unsigned key = (unsigned)(mr & 7) << 4;
    const unsigned e0 = (unsigned)mr * 128u + (((unsigned)kg * 16u) ^ key);
    const unsigned e1 = (unsigned)mr * 128u + ((64u + (unsigned)kg * 16u) ^ key);
    const unsigned bbase = (unsigned)(wn & 1) * 8192u;
    const unsigned bhalf = (unsigned)(wn >> 1) * 16384u;

#pragma unroll
    for (int m = 0; m < 8; ++m)
#pragma unroll
        for (int n = 0; n < 4; ++n) acc[m][n] = (f32x4){0.f, 0.f, 0.f, 0.f};

    auto stg = [&](int kt, unsigned srcb, const u16* G, int region, int halfo) {
        char* dst = lds + region + (kt & 1) * 32768 + halfo + t * 16;
        const u16* g = G + srcb + (unsigned)kt * 64u;
        gl16(g, dst);
        gl16(g + 65536, dst + 8192);
    };

    stg(0, sAlo, Ap, 0, 0);      stg(0, sAhi, Ap, 0, 16384);
    stg(0, sBlo, Bp, 65536, 0);  stg(0, sBhi, Bp, 65536, 16384);
    stg(1, sAlo, Ap, 0, 0);      stg(1, sAhi, Ap, 0, 16384);
    stg(1, sBlo, Bp, 65536, 0);  stg(1, sBhi, Bp, 65536, 16384);
    WAIT_VM(8);
    BARRIER();

    f16x8 a[4][2], b01[2][2], b23[2][2];

    {
        char* LB = lds + 65536 + bhalf;
#pragma unroll
        for (int n = 0; n < 2; ++n) {
            b01[n][0] = *(const f16x8*)(LB + bbase + n * 2048 + e0);
            b01[n][1] = *(const f16x8*)(LB + bbase + n * 2048 + e1);
        }
    }

#pragma unroll 1
    for (int kt = 0; kt < NT; ++kt) {
        char* LA = lds + (kt & 1) * 32768 + wm * 16384;
        char* LB = lds + 65536 + (kt & 1) * 32768 + bhalf;

        // P1: read a0-3; stage A-lo(t+1); MFMA m0-3 x b01
#pragma unroll
        for (int i = 0; i < 4; ++i) {
            a[i][0] = *(const f16x8*)(LA + i * 2048 + e0);
            a[i][1] = *(const f16x8*)(LA + i * 2048 + e1);
        }
        if (kt + 1 < NT) stg(kt + 1, sAlo, Ap, 0, 0);
        BARRIER();
        __builtin_amdgcn_s_setprio(1);
#pragma unroll
        for (int i = 0; i < 4; ++i)
#pragma unroll
            for (int n = 0; n < 2; ++n) {
                acc[i][n] = MFMA16(a[i][0], b01[n][0], acc[i][n]);
                acc[i][n] = MFMA16(a[i][1], b01[n][1], acc[i][n]);
            }
        __builtin_amdgcn_s_setprio(0);
        BARRIER();

        // P2: read b23; stage A-hi(t+1); MFMA m0-3 x b23
#pragma unroll
        for (int n = 0; n < 2; ++n) {
            b23[n][0] = *(const f16x8*)(LB + bbase + (2 + n) * 2048 + e0);
            b23[n][1] = *(const f16x8*)(LB + bbase + (2 + n) * 2048 + e1);
        }
        if (kt + 1 < NT) stg(kt + 1, sAhi, Ap, 0, 16384);
        BARRIER();
        __builtin_amdgcn_s_setprio(1);
#pragma unroll
        for (int i = 0; i < 4; ++i)
#pragma unroll
            for (int n = 0; n < 2; ++n) {
                acc[i][2 + n] = MFMA16(a[i][0], b23[n][0], acc[i][2 + n]);
                acc[i][2 + n] = MFMA16(a[i][1], b23[n][1], acc[i][2 + n]);
            }
        __builtin_amdgcn_s_setprio(0);
        BARRIER();

        // P3: read a4-7; stage B-lo(t+2); MFMA m4-7 x b23
#pragma unroll
        for (int i = 0; i < 4; ++i) {
            a[i][0] = *(const f16x8*)(LA + (4 + i) * 2048 + e0);
            a[i][1] = *(const f16x8*)(LA + (4 + i) * 2048 + e1);
        }
        if (kt + 2 < NT) stg(kt + 2, sBlo, Bp, 65536, 0);
        BARRIER();
        __builtin_amdgcn_s_setprio(1);
#pragma unroll
        for (int i = 0; i < 4; ++i)
#pragma unroll
            for (int n = 0; n < 2; ++n) {
                acc[4 + i][2 + n] = MFMA16(a[i][0], b23[n][0], acc[4 + i][2 + n]);
                acc[4 + i][2 + n] = MFMA16(a[i][1], b23[n][1], acc[4 + i][2 + n]);
            }
        __builtin_amdgcn_s_setprio(0);
        BARRIER();

        // P4: stage B-hi(t+2); MFMA m4-7 x b01; gates; read b01(t+1)
        if (kt + 2 < NT) stg(kt + 2, sBhi, Bp, 65536, 16384);
        BARRIER();
        __builtin_amdgcn_s_setprio(1);
#pragma unroll
        for (int i = 0; i < 4; ++i)
#pragma unroll
            for (int n = 0; n < 2; ++n) {
                acc[4 + i][n] = MFMA16(a[i][0], b01[n][0], acc[4 + i][n]);
                acc[4 + i][n] = MFMA16(a[i][1], b01[n][1], acc[4 + i][n]);
            }
        __builtin_amdgcn_s_setprio(0);
        if (kt + 1 < NT) {
            if (kt + 2 < NT) { WAIT_VM(8); } else { WAIT_VM(4); }
            char* LB2 = lds + 65536 + ((kt + 1) & 1) * 32768 + bhalf;
#pragma unroll
            for (int n = 0; n < 2; ++n) {
                b01[n][0] = *(const f16x8*)(LB2 + bbase + n * 2048 + e0);
                b01[n][1] = *(const f16x8*)(LB2 + bbase + n * 2048 + e1);
            }
            if (kt + 2 < NT) { WAIT_VM(4); } else { WAIT_VM(0); }
        }
        BARRIER();
    }
}

// ---------------------------------------------------------------------------
// GEMM1: d = sigmoid(X @ T^T), store d f16 (frozen)
// ---------------------------------------------------------------------------
__global__ __launch_bounds__(512, 2) void gemm1_8p(
    const u16* __restrict__ Xh, const u16* __restrict__ Th,
    u16* __restrict__ dval)
{
    __shared__ __align__(16) char lds[131072];
    int rb, cb;
    block_map(blockIdx.x, rb, cb);
    f32x4 acc[8][4];
    gemm_core8<16>(Xh, Th, rb, cb, lds, acc);

    const int lane = threadIdx.x & 63, wid = threadIdx.x >> 6;
    const int wm = wid >> 2, wn = wid & 3;
    const int mr = lane & 15, fq = (lane >> 4) * 4;
#pragma unroll
    for (int m = 0; m < 8; ++m)
#pragma unroll
        for (int j = 0; j < 4; ++j) {
            int grow = rb + wm * 128 + m * 16 + fq + j;
#pragma unroll
            for (int n = 0; n < 4; ++n) {
                int gcol = cb + wn * 64 + n * 16 + mr;
                float s = acc[m][n][j];
                float d = 1.0f / (1.0f + __expf(-s));
                dval[(size_t)grow * NPAD + gcol] = f2h(d);
            }
        }
}

// ---------------------------------------------------------------------------
// tree expansion: one wave per row; lane l owns leaves l*16..l*16+15.
// Output written FRAGMENT-PACKED for gemm2sm:
//   Apk[rb64*65536 + kt*2048 + m*512 + (kg*16+mr)*8 + j] = prob[row][kt*32+kg*8+j]
//   (row = rb64*64 + m*16 + mr; lane l -> kt = l>>1, kg base = (l&1)*2)
// ---------------------------------------------------------------------------
__global__ __launch_bounds__(256) void probs_kernel(const u16* __restrict__ dval,
                                                    u16* __restrict__ Apk) {
    const int t = threadIdx.x, w = t >> 6, l = t & 63;
    const int row = (blockIdx.x << 2) + w;
    const u16* dp = dval + (size_t)row * NPAD;

    float prod = 1.0f;
#pragma unroll
    for (int lev = 0; lev < 6; lev++) {
        int node = (1 << lev) - 1 + (l >> (6 - lev));
        int bit  = (l >> (5 - lev)) & 1;
        float v = h2f(dp[node]);
        prod *= bit ? (1.0f - v) : v;
    }
    float d6 = h2f(dp[63 + l]);
    float d7[2], d8[4], d9[8];
#pragma unroll
    for (int j = 0; j < 2; j++) d7[j] = h2f(dp[127 + 2 * l + j]);
#pragma unroll
    for (int j = 0; j < 4; j++) d8[j] = h2f(dp[255 + 4 * l + j]);
#pragma unroll
    for (int j = 0; j < 8; j++) d9[j] = h2f(dp[511 + 8 * l + j]);

    u16 outv[16];
#pragma unroll
    for (int j = 0; j < 16; j++) {
        float f6 = (j >> 3) ? (1.0f - d6) : d6;
        float v7 = d7[j >> 3];  float f7 = ((j >> 2) & 1) ? (1.0f - v7) : v7;
        float v8 = d8[j >> 2];  float f8 = ((j >> 1) & 1) ? (1.0f - v8) : v8;
        float v9 = d9[j >> 1];  float f9 = (j & 1) ? (1.0f - v9) : v9;
        outv[j] = f2h(prod * f6 * f7 * f8 * f9);
    }

    // packed write: two 16B stores (kg0 covers leaves q=0..7, kg0+1 q=8..15)
    const int rb64 = row >> 6, m = (row >> 4) & 3, mrr = row & 15;
    const int kg0 = (l & 1) * 2;
    u16* base = Apk + (size_t)rb64 * 65536 + (l >> 1) * 2048 + m * 512;
    *(u16x8*)(base + (kg0 * 16 + mrr) * 8) =
        (u16x8){outv[0], outv[1], outv[2], outv[3], outv[4], outv[5], outv[6], outv[7]};
    *(u16x8*)(base + ((kg0 + 1) * 16 + mrr) * 8) =
        (u16x8){outv[8], outv[9], outv[10], outv[11], outv[12], outv[13], outv[14], outv[15]};
}

// ---------------------------------------------------------------------------
// FUSED GEMM2 + SOFTMAX, round 10: BOTH operands fragment-packed in global ->
// direct-to-register, perfectly coalesced (wave-uniform base + lane*16B).
// Block = 64 full rows (rb64 = blockIdx.x), 1024 threads / 16 waves; wave wid
// owns cols wid*64: acc[4][4]. NO LDS / barriers in K-loop. b reg-dbuf
// (one-step prefetch, unroll-2); a single-buf reloaded after MFMA (L1-hot:
// all 16 waves read the same 4KB A-step). Softmax epilogue via 8KB LDS.
// ---------------------------------------------------------------------------
__global__ __launch_bounds__(1024, 1) void gemm2sm(
    const u16* __restrict__ Apk, const u16* __restrict__ Bpk,
    float* __restrict__ out)
{
    __shared__ __align__(16) char lds[8192];
    const int t = threadIdx.x, wid = t >> 6, lane = t & 63;
    const int mr = lane & 15, kg = lane >> 4;

    const u16* abase = Apk + (size_t)blockIdx.x * 65536 + (unsigned)lane * 8u;
    const u16* bbase = Bpk + (size_t)(wid * 4) * 16384 + (unsigned)lane * 8u;

    f32x4 acc[4][4];
#pragma unroll
    for (int m = 0; m < 4; ++m)
#pragma unroll
        for (int n = 0; n < 4; ++n) acc[m][n] = (f32x4){0.f, 0.f, 0.f, 0.f};

    f16x8 aR[4], bA[4], bB[4];

    // prologue: b(0), a(0)
#pragma unroll
    for (int n = 0; n < 4; ++n) bA[n] = *(const f16x8*)(bbase + n * 16384);
#pragma unroll
    for (int m = 0; m < 4; ++m) aR[m] = *(const f16x8*)(abase + m * 512);

    auto step = [&](int kt, f16x8 (&bu)[4], f16x8 (&bl)[4]) {
        if (kt + 1 < 32) {
#pragma unroll
            for (int n = 0; n < 4; ++n)
                bl[n] = *(const f16x8*)(bbase + n * 16384 + (unsigned)(kt + 1) * 512u);
        }
        __builtin_amdgcn_s_setprio(1);
#pragma unroll
        for (int m = 0; m < 4; ++m)
#pragma unroll
            for (int n = 0; n < 4; ++n)
                acc[m][n] = MFMA16(aR[m], bu[n], acc[m][n]);
        __builtin_amdgcn_s_setprio(0);
        if (kt + 1 < 32) {
#pragma unroll
            for (int m = 0; m < 4; ++m)
                aR[m] = *(const f16x8*)(abase + (unsigned)(kt + 1) * 2048u + m * 512);
        }
    };

#pragma unroll 1
    for (int k2 = 0; k2 < 16; ++k2) {
        step(2 * k2, bA, bB);
        step(2 * k2 + 1, bB, bA);
    }

    // ---------------- in-register softmax over full rows ----------------
    // thread rows: r(m,j) = m*16 + kg*4 + j; cols: wid*64 + n*16 + mr
    float* red  = (float*)lds;           // [64][16] max
    float* red2 = (float*)(lds + 4096);  // [64][16] sum
    const int fq = kg * 4;
    const int rb = blockIdx.x * 64;

    float mx[4][4];
#pragma unroll
    for (int m = 0; m < 4; ++m)
#pragma unroll
        for (int j = 0; j < 4; ++j) {
            float v = acc[m][0][j];
#pragma unroll
            for (int n = 1; n < 4; ++n) v = fmaxf(v, acc[m][n][j]);
#pragma unroll
            for (int off = 1; off < 16; off <<= 1)
                v = fmaxf(v, __shfl_xor(v, off));
            mx[m][j] = v;
        }
    if (mr == 0) {
#pragma unroll
        for (int m = 0; m < 4; ++m)
#pragma unroll
            for (int j = 0; j < 4; ++j)
                red[(m * 16 + fq + j) * 16 + wid] = mx[m][j];
    }
    __syncthreads();
    if (t < 64) {
        float v = red[t * 16];
#pragma unroll
        for (int w = 1; w < 16; ++w) v = fmaxf(v, red[t * 16 + w]);
        red[t * 16] = v;
    }
    __syncthreads();

    float sm[4][4];
#pragma unroll
    for (int m = 0; m < 4; ++m)
#pragma unroll
        for (int j = 0; j < 4; ++j) {
            float M = red[(m * 16 + fq + j) * 16];
            float s = 0.f;
#pragma unroll
            for (int n = 0; n < 4; ++n) {
                float e = __expf(acc[m][n][j] - M);
                acc[m][n][j] = e;
                s += e;
            }
#pragma unroll
            for (int off = 1; off < 16; off <<= 1)
                s += __shfl_xor(s, off);
            sm[m][j] = s;
        }
    if (mr == 0) {
#pragma unroll
        for (int m = 0; m < 4; ++m)
#pragma unroll
            for (int j = 0; j < 4; ++j)
                red2[(m * 16 + fq + j) * 16 + wid] = sm[m][j];
    }
    __syncthreads();
    if (t < 64) {
        float v = 0.f;
#pragma unroll
        for (int w = 0; w < 16; ++w) v += red2[t * 16 + w];
        red2[t * 16] = 1.0f / v;
    }
    __syncthreads();

#pragma unroll
    for (int m = 0; m < 4; ++m)
#pragma unroll
        for (int j = 0; j < 4; ++j) {
            int grow = rb + m * 16 + fq + j;
            float inv = red2[(m * 16 + fq + j) * 16];
#pragma unroll
            for (int n = 0; n < 4; ++n) {
                int gcol = wid * 64 + n * 16 + mr;
                out[(size_t)grow * 1024 + gcol] = acc[m][n][j] * inv;
            }
        }
}

// ---------------------------------------------------------------------------
extern "C" void kernel_launch(void* const* d_in, const int* in_sizes, int n_in,
                              void* d_out, int out_size, void* d_ws, size_t ws_size,
                              hipStream_t stream) {
    const float* x  = (const float*)d_in[0];
    const float* ft = (const float*)d_in[1];
    const float* lp = (const float*)d_in[2];
    float* out = (float*)d_out;
    char* ws = (char*)d_ws;

    // ws layout: Xh 64Mi | Th 2Mi | Bpk 2Mi | dval 64Mi | Apk 64Mi
    u16* Xh  = (u16*)ws;
    u16* Th  = (u16*)(ws + (size_t)67108864);
    u16* Bpk = Th + (size_t)NPAD * DIM;
    u16* dval = (u16*)(ws + (size_t)67108864 + 2 * 2097152);
    u16* Apk  = dval + (size_t)BATCH * NPAD;

    prep_x<<<4096, 256, 0, stream>>>((const float4*)x, Xh, BATCH * DIM / 4);
    prep_t<<<4096, 256, 0, stream>>>(ft, Th);
    prep_lt<<<1024, 256, 0, stream>>>(lp, Bpk);
    gemm1_8p<<<512, 512, 0, stream>>>(Xh, Th, dval);
    probs_kernel<<<8192, 256, 0, stream>>>(dval, Apk);
    gemm2sm<<<512, 1024, 0, stream>>>(Apk, Bpk, out);
}